// Round 1
// baseline (71062.152 us; speedup 1.0000x reference)
//
#include <hip/hip_runtime.h>
#include <math.h>

// RNNAttentionDecoder on MI355X — round 1: correctness-first multi-kernel design.
// All math f32 (argmax feedback forbids bf16; no fp32 MFMA exists on CDNA4).
// Activations kept transposed [feature][batch=32] for coalesced lane access.
// 4 kernels per step x 300 steps; argmax via packed u64 atomicMax.

typedef unsigned long long u64;

#define NB 32
#define NS 196
#define ND 512
#define NK 256
#define NV 10000
#define NT 300

__device__ __forceinline__ float sigm(float x) { return 1.0f / (1.0f + expf(-x)); }

// monotone f32 -> u32, packed with (0xFFFFFFFF - v) so max() = (max value, then smallest idx)
__device__ __forceinline__ u64 packmax(float x, int v) {
  unsigned u = __float_as_uint(x);
  u = (u & 0x80000000u) ? ~u : (u | 0x80000000u);
  return ((u64)u << 32) | (u64)(0xFFFFFFFFu - (unsigned)v);
}

// skewed LDS slot: conflict-free for both j-fastest writes and b-fastest reads
#define ESLOT(j, bb) (((j) << 5) + (((bb) + (j)) & 31))

// ---------------- init: zero state + seed argmax slot1 with tok=0 ----------------
__global__ __launch_bounds__(256) void k_init(float* __restrict__ z, u64* __restrict__ amax) {
  int g = blockIdx.x * 256 + threadIdx.x;
  if (g < 122880) z[g] = 0.0f;          // h0t[2], h1t[2], c0, c1, P
  if (g < 512) {
    u64 v = 0ull;
    if (g >= 256 && g < 288) v = (1ull << 32) | 0xFFFFFFFFull;  // slot1 sub0: decodes tok=0
    amax[g] = v;
  }
}

// ---------------- keys/values: (B,S,512)@(512,256)^T, once ----------------
// grid (8 k-chunks, 32 b); thread=(k fastest 32, s-group 8); W row stays in regs, x broadcast.
__global__ __launch_bounds__(256) void k_kv(
    const float* __restrict__ x, const float* __restrict__ Wk, const float* __restrict__ bk,
    const float* __restrict__ Wv, const float* __restrict__ bv,
    float* __restrict__ keys, float* __restrict__ values) {
  const int kc = blockIdx.x, b = blockIdx.y;
  const int t = threadIdx.x;
  const int kl = t & 31, sg = t >> 5;
  const int k = kc * 32 + kl;
  float ak[25], av[25];
#pragma unroll
  for (int i = 0; i < 25; ++i) { ak[i] = 0.f; av[i] = 0.f; }
  const float* wkr = Wk + (size_t)k * ND;
  const float* wvr = Wv + (size_t)k * ND;
  const float* xb = x + (size_t)b * NS * ND;
  for (int j = 0; j < ND; j += 4) {
    const float4 wk4 = *(const float4*)(wkr + j);
    const float4 wv4 = *(const float4*)(wvr + j);
#pragma unroll
    for (int si = 0; si < 25; ++si) {
      const int s = sg + si * 8;
      if (s < NS) {
        const float4 xv = *(const float4*)(xb + (size_t)s * ND + j);
        ak[si] += wk4.x * xv.x + wk4.y * xv.y + wk4.z * xv.z + wk4.w * xv.w;
        av[si] += wv4.x * xv.x + wv4.y * xv.y + wv4.z * xv.z + wv4.w * xv.w;
      }
    }
  }
  const float bkk = bk[k], bvv = bv[k];
#pragma unroll
  for (int si = 0; si < 25; ++si) {
    const int s = sg + si * 8;
    if (s < NS) {
      const size_t o = ((size_t)b * NS + s) * NK + k;
      keys[o] = ak[si] + bkk;
      values[o] = av[si] + bvv;
    }
  }
}

// ---------------- LSTM cell 0 ----------------
// 256 blocks, 2 d-units each; thread=(d_local,gate,b). Inline embed gather into skewed LDS.
// Inputs: emb[tok] (512) | ctx = P rows 512..767 | h0_prev (transposed). Writes h0t[nxt], c0.
__global__ __launch_bounds__(256) void k_lstm0(
    const float* __restrict__ Wih, const float* __restrict__ Whh,
    const float* __restrict__ bih, const float* __restrict__ bhh,
    const float* __restrict__ emb, const float* __restrict__ P,
    const float* __restrict__ h_in, float* __restrict__ h_out, float* __restrict__ c,
    const u64* __restrict__ amax_prev) {
  __shared__ float E[256 * 32];
  __shared__ float g_lds[2][4][32];
  __shared__ int tok_lds[32];
  const int t = threadIdx.x;
  if (t < 32) {
    u64 m = amax_prev[t];
#pragma unroll
    for (int s2 = 1; s2 < 8; ++s2) {
      const u64 o = amax_prev[s2 * 32 + t];
      m = (o > m) ? o : m;
    }
    tok_lds[t] = (int)(0xFFFFFFFFu - (unsigned)(m & 0xFFFFFFFFull));
  }
  __syncthreads();
  const int dl = t >> 7, gate = (t >> 5) & 3, b = t & 31;
  const int d = blockIdx.x * 2 + dl;
  const int r = gate * ND + d;
  float acc = bih[r] + bhh[r];
  const float* wi = Wih + (size_t)r * 768;
  for (int half = 0; half < 2; ++half) {
    // stage 32 embed rows (256 cols) coalesced; skewed slots keep LDS conflict-free
    for (int n = 0; n < 32; ++n) {
      E[ESLOT(t, n)] = emb[(size_t)tok_lds[n] * ND + half * 256 + t];
    }
    __syncthreads();
    const float* wih = wi + half * 256;
    for (int j = 0; j < 256; j += 4) {
      const float4 w = *(const float4*)(wih + j);
      acc += w.x * E[ESLOT(j + 0, b)] + w.y * E[ESLOT(j + 1, b)]
           + w.z * E[ESLOT(j + 2, b)] + w.w * E[ESLOT(j + 3, b)];
    }
    __syncthreads();
  }
  // ctx part: Wih cols 512..767 <-> P rows 512..767
  for (int j = 0; j < 256; j += 4) {
    const float4 w = *(const float4*)(wi + 512 + j);
    acc += w.x * P[(512 + j) * 32 + b] + w.y * P[(513 + j) * 32 + b]
         + w.z * P[(514 + j) * 32 + b] + w.w * P[(515 + j) * 32 + b];
  }
  const float* wh = Whh + (size_t)r * ND;
  for (int j = 0; j < ND; j += 4) {
    const float4 w = *(const float4*)(wh + j);
    acc += w.x * h_in[(j + 0) * 32 + b] + w.y * h_in[(j + 1) * 32 + b]
         + w.z * h_in[(j + 2) * 32 + b] + w.w * h_in[(j + 3) * 32 + b];
  }
  g_lds[dl][gate][b] = acc;
  __syncthreads();
  if (t < 64) {
    const int dl2 = t >> 5, b2 = t & 31;
    const int idx = (blockIdx.x * 2 + dl2) * 32 + b2;
    const float gi = g_lds[dl2][0][b2], gf = g_lds[dl2][1][b2];
    const float gg = g_lds[dl2][2][b2], go = g_lds[dl2][3][b2];
    const float cn = sigm(gf) * c[idx] + sigm(gi) * tanhf(gg);
    c[idx] = cn;
    h_out[idx] = sigm(go) * tanhf(cn);
  }
}

// ---------------- LSTM cell 1 ---------------- writes h1t[nxt], c1, and P rows 0..511
__global__ __launch_bounds__(256) void k_lstm1(
    const float* __restrict__ Wih, const float* __restrict__ Whh,
    const float* __restrict__ bih, const float* __restrict__ bhh,
    const float* __restrict__ h0n, const float* __restrict__ h1c,
    float* __restrict__ h1n, float* __restrict__ c, float* __restrict__ P) {
  __shared__ float g_lds[2][4][32];
  const int t = threadIdx.x;
  const int dl = t >> 7, gate = (t >> 5) & 3, b = t & 31;
  const int d = blockIdx.x * 2 + dl;
  const int r = gate * ND + d;
  float acc = bih[r] + bhh[r];
  const float* wi = Wih + (size_t)r * ND;
  const float* wh = Whh + (size_t)r * ND;
  for (int j = 0; j < ND; j += 4) {
    const float4 a4 = *(const float4*)(wi + j);
    acc += a4.x * h0n[(j + 0) * 32 + b] + a4.y * h0n[(j + 1) * 32 + b]
         + a4.z * h0n[(j + 2) * 32 + b] + a4.w * h0n[(j + 3) * 32 + b];
  }
  for (int j = 0; j < ND; j += 4) {
    const float4 a4 = *(const float4*)(wh + j);
    acc += a4.x * h1c[(j + 0) * 32 + b] + a4.y * h1c[(j + 1) * 32 + b]
         + a4.z * h1c[(j + 2) * 32 + b] + a4.w * h1c[(j + 3) * 32 + b];
  }
  g_lds[dl][gate][b] = acc;
  __syncthreads();
  if (t < 64) {
    const int dl2 = t >> 5, b2 = t & 31;
    const int idx = (blockIdx.x * 2 + dl2) * 32 + b2;
    const float gi = g_lds[dl2][0][b2], gf = g_lds[dl2][1][b2];
    const float gg = g_lds[dl2][2][b2], go = g_lds[dl2][3][b2];
    const float cn = sigm(gf) * c[idx] + sigm(gi) * tanhf(gg);
    c[idx] = cn;
    const float hn = sigm(go) * tanhf(cn);
    h1n[idx] = hn;
    P[idx] = hn;  // h1 section of pred input
  }
}

// ---------------- attention: one block per batch row ----------------
// q = h1@Wq^T+bq (pre-scaled); energy over 196 keys; softmax; ctx -> P rows 512..767.
// Also resets the current argmax slot before k_pred's atomicMax.
__global__ __launch_bounds__(256) void k_att(
    float* __restrict__ P, const float* __restrict__ Wq, const float* __restrict__ bq,
    const float* __restrict__ keys, const float* __restrict__ values,
    u64* __restrict__ amax_cur) {
  const int b = blockIdx.x, t = threadIdx.x;
  __shared__ float q_lds[256];
  __shared__ float attn[256];
  __shared__ float red[256];
  if (t < 8) amax_cur[t * 32 + b] = 0ull;
  {
    float acc = bq[t];
    const float* wq = Wq + (size_t)t * ND;
    for (int j = 0; j < ND; j += 4) {
      const float4 w = *(const float4*)(wq + j);
      acc += w.x * P[(j + 0) * 32 + b] + w.y * P[(j + 1) * 32 + b]
           + w.z * P[(j + 2) * 32 + b] + w.w * P[(j + 3) * 32 + b];
    }
    q_lds[t] = acc * 0.0625f;  // 1/sqrt(256)
  }
  __syncthreads();
  float e = -INFINITY;
  if (t < NS) {
    const float* kr = keys + ((size_t)b * NS + t) * NK;
    float a0 = 0.f, a1 = 0.f, a2 = 0.f, a3 = 0.f;
    for (int k = 0; k < NK; k += 8) {
      const float4 k0 = *(const float4*)(kr + k);
      const float4 k1 = *(const float4*)(kr + k + 4);
      a0 += k0.x * q_lds[k + 0] + k0.y * q_lds[k + 1];
      a1 += k0.z * q_lds[k + 2] + k0.w * q_lds[k + 3];
      a2 += k1.x * q_lds[k + 4] + k1.y * q_lds[k + 5];
      a3 += k1.z * q_lds[k + 6] + k1.w * q_lds[k + 7];
    }
    e = (a0 + a1) + (a2 + a3);
  }
  red[t] = e;
  __syncthreads();
  for (int off = 128; off; off >>= 1) { if (t < off) red[t] = fmaxf(red[t], red[t + off]); __syncthreads(); }
  const float m = red[0];
  __syncthreads();
  const float a = (t < NS) ? expf(e - m) : 0.f;
  red[t] = a;
  __syncthreads();
  for (int off = 128; off; off >>= 1) { if (t < off) red[t] += red[t + off]; __syncthreads(); }
  const float inv = 1.0f / red[0];
  attn[t] = a * inv;
  __syncthreads();
  {
    const float* vb = values + (size_t)b * NS * NK + t;
    float c0_ = 0.f, c1_ = 0.f, c2_ = 0.f, c3_ = 0.f;
    for (int s = 0; s < NS; s += 4) {  // 196 = 4*49 exact
      c0_ += attn[s + 0] * vb[(size_t)(s + 0) * NK];
      c1_ += attn[s + 1] * vb[(size_t)(s + 1) * NK];
      c2_ += attn[s + 2] * vb[(size_t)(s + 2) * NK];
      c3_ += attn[s + 3] * vb[(size_t)(s + 3) * NK];
    }
    P[(512 + t) * 32 + b] = (c0_ + c1_) + (c2_ + c3_);
  }
}

// ---------------- pred GEMM (32 x 10000, K=768) + per-block argmax partials ----------------
// thread tile 2v x 2b; coalesced float2 stores over v; packed u64 atomicMax into 8 sub-slots.
__global__ __launch_bounds__(256) void k_pred(
    const float* __restrict__ P, const float* __restrict__ Wp, const float* __restrict__ bp,
    float* __restrict__ out, u64* __restrict__ amax_cur, int step) {
  __shared__ u64 cand[32][16];
  const int t = threadIdx.x;
  const int bg = t >> 4, vg = t & 15;
  const int b = bg * 2;
  const int v = blockIdx.x * 32 + vg * 2;
  const bool vok0 = v < NV, vok1 = (v + 1) < NV;
  const int vc0 = vok0 ? v : (NV - 1);
  const int vc1 = vok1 ? (v + 1) : (NV - 1);
  const float* w0 = Wp + (size_t)vc0 * 768;
  const float* w1 = Wp + (size_t)vc1 * 768;
  float p00 = bp[vc0], p01 = bp[vc0], p10 = bp[vc1], p11 = bp[vc1];
  for (int j = 0; j < 768; j += 2) {
    const float2 in0 = *(const float2*)&P[(j + 0) * 32 + b];
    const float2 in1 = *(const float2*)&P[(j + 1) * 32 + b];
    const float2 wa = *(const float2*)(w0 + j);
    const float2 wb = *(const float2*)(w1 + j);
    p00 += wa.x * in0.x + wa.y * in1.x;
    p01 += wa.x * in0.y + wa.y * in1.y;
    p10 += wb.x * in0.x + wb.y * in1.x;
    p11 += wb.x * in0.y + wb.y * in1.y;
  }
  const size_t ro0 = ((size_t)b * NT + step) * NV;
  const size_t ro1 = ((size_t)(b + 1) * NT + step) * NV;
  if (vok1) {
    *(float2*)&out[ro0 + v] = make_float2(p00, p10);
    *(float2*)&out[ro1 + v] = make_float2(p01, p11);
  } else if (vok0) {
    out[ro0 + v] = p00;
    out[ro1 + v] = p01;
  }
  u64 c0 = 0ull, c1 = 0ull;
  if (vok0) { c0 = packmax(p00, v); c1 = packmax(p01, v); }
  if (vok1) {
    const u64 a0 = packmax(p10, v + 1); if (a0 > c0) c0 = a0;
    const u64 a1 = packmax(p11, v + 1); if (a1 > c1) c1 = a1;
  }
  cand[b][vg] = c0;
  cand[b + 1][vg] = c1;
  __syncthreads();
  if (t < 32) {
    u64 m = cand[t][0];
#pragma unroll
    for (int i = 1; i < 16; ++i) { const u64 o = cand[t][i]; if (o > m) m = o; }
    atomicMax(&amax_cur[(blockIdx.x & 7) * 32 + t], m);
  }
}

// ---------------- host ----------------
extern "C" void kernel_launch(void* const* d_in, const int* in_sizes, int n_in,
                              void* d_out, int out_size, void* d_ws, size_t ws_size,
                              hipStream_t stream) {
  (void)in_sizes; (void)n_in; (void)out_size; (void)ws_size;
  const float* x    = (const float*)d_in[0];
  const float* emb  = (const float*)d_in[1];
  const float* Wk   = (const float*)d_in[2];
  const float* bk   = (const float*)d_in[3];
  const float* Wv   = (const float*)d_in[4];
  const float* bv   = (const float*)d_in[5];
  const float* Wq   = (const float*)d_in[6];
  const float* bq   = (const float*)d_in[7];
  const float* Wp   = (const float*)d_in[8];
  const float* bp   = (const float*)d_in[9];
  const float* Wih0 = (const float*)d_in[10];
  const float* Whh0 = (const float*)d_in[11];
  const float* bih0 = (const float*)d_in[12];
  const float* bhh0 = (const float*)d_in[13];
  const float* Wih1 = (const float*)d_in[14];
  const float* Whh1 = (const float*)d_in[15];
  const float* bih1 = (const float*)d_in[16];
  const float* bhh1 = (const float*)d_in[17];
  float* out = (float*)d_out;

  // workspace layout (floats): ~12.8 MB total
  float* ws     = (float*)d_ws;
  float* keys   = ws;                        // 32*196*256 = 1605632
  float* values = keys + 1605632;            // 1605632
  float* h0t    = values + 1605632;          // [2][512*32] = 32768
  float* h1t    = h0t + 32768;               // 32768
  float* c0     = h1t + 32768;               // 16384
  float* c1     = c0 + 16384;                // 16384
  float* P      = c1 + 16384;                // [768][32] = 24576 (h1 | ctx)
  u64*   amax   = (u64*)(P + 24576);         // [2][8][32] packed argmax slots

  k_init<<<480, 256, 0, stream>>>(h0t, amax);
  k_kv<<<dim3(8, 32), 256, 0, stream>>>(x, Wk, bk, Wv, bv, keys, values);

  for (int step = 0; step < NT; ++step) {
    const int cur = step & 1, nxt = cur ^ 1;
    k_lstm0<<<256, 256, 0, stream>>>(Wih0, Whh0, bih0, bhh0, emb, P,
                                     h0t + cur * 16384, h0t + nxt * 16384, c0,
                                     amax + nxt * 256);
    k_lstm1<<<256, 256, 0, stream>>>(Wih1, Whh1, bih1, bhh1,
                                     h0t + nxt * 16384, h1t + cur * 16384,
                                     h1t + nxt * 16384, c1, P);
    k_att<<<32, 256, 0, stream>>>(P, Wq, bq, keys, values, amax + cur * 256);
    k_pred<<<313, 256, 0, stream>>>(P, Wp, bp, out, amax + cur * 256, step);
  }
}

// Round 2
// 43670.551 us; speedup vs baseline: 1.6272x; 1.6272x over previous
//
#include <hip/hip_runtime.h>
#include <math.h>

// RNNAttentionDecoder on MI355X — round 2: kill scattered-row VMEM patterns.
// Row-broadcast matvec everywhere: wave lane=(row-parity, b); W reads are
// 2-line broadcasts; activation vector transposed into LDS [b][k] (stride
// pad ≡ 4 mod 32 -> optimal 4-phase ds_read_b128). All f32 (argmax feedback
// forbids bf16; no fp32 MFMA on CDNA4).

typedef unsigned long long u64;

#define NB 32
#define NS 196
#define ND 512
#define NK 256
#define NV 10000
#define NT 300

__device__ __forceinline__ float sigm(float x) { return 1.0f / (1.0f + expf(-x)); }

// monotone f32 -> u32, packed with (0xFFFFFFFF - v) so max() = (max value, then smallest idx)
__device__ __forceinline__ u64 packmax(float x, int v) {
  unsigned u = __float_as_uint(x);
  u = (u & 0x80000000u) ? ~u : (u | 0x80000000u);
  return ((u64)u << 32) | (u64)(0xFFFFFFFFu - (unsigned)v);
}

// ---------------- init: zero state + seed argmax slot1 with tok=0 ----------------
__global__ __launch_bounds__(256) void k_init(float* __restrict__ z, u64* __restrict__ amax) {
  int g = blockIdx.x * 256 + threadIdx.x;
  if (g < 122880) z[g] = 0.0f;          // h0t[2], h1t[2], c0, c1, P
  if (g < 512) {
    u64 v = 0ull;
    if (g >= 256 && g < 288) v = (1ull << 32) | 0xFFFFFFFFull;  // slot1 sub0: decodes tok=0
    amax[g] = v;
  }
}

// ---------------- keys/values: (B,S,512)@(512,256)^T, once ----------------
__global__ __launch_bounds__(256) void k_kv(
    const float* __restrict__ x, const float* __restrict__ Wk, const float* __restrict__ bk,
    const float* __restrict__ Wv, const float* __restrict__ bv,
    float* __restrict__ keys, float* __restrict__ values) {
  const int kc = blockIdx.x, b = blockIdx.y;
  const int t = threadIdx.x;
  const int kl = t & 31, sg = t >> 5;
  const int k = kc * 32 + kl;
  float ak[25], av[25];
#pragma unroll
  for (int i = 0; i < 25; ++i) { ak[i] = 0.f; av[i] = 0.f; }
  const float* wkr = Wk + (size_t)k * ND;
  const float* wvr = Wv + (size_t)k * ND;
  const float* xb = x + (size_t)b * NS * ND;
  for (int j = 0; j < ND; j += 4) {
    const float4 wk4 = *(const float4*)(wkr + j);
    const float4 wv4 = *(const float4*)(wvr + j);
#pragma unroll
    for (int si = 0; si < 25; ++si) {
      const int s = sg + si * 8;
      if (s < NS) {
        const float4 xv = *(const float4*)(xb + (size_t)s * ND + j);
        ak[si] += wk4.x * xv.x + wk4.y * xv.y + wk4.z * xv.z + wk4.w * xv.w;
        av[si] += wv4.x * xv.x + wv4.y * xv.y + wv4.z * xv.z + wv4.w * xv.w;
      }
    }
  }
  const float bkk = bk[k], bvv = bv[k];
#pragma unroll
  for (int si = 0; si < 25; ++si) {
    const int s = sg + si * 8;
    if (s < NS) {
      const size_t o = ((size_t)b * NS + s) * NK + k;
      keys[o] = ak[si] + bkk;
      values[o] = av[si] + bvv;
    }
  }
}

// ---------------- LSTM cell 0 ----------------
// 256 blocks x 8 gate-rows. inT[b][0..511]=emb[tok[b]], [512..767]=ctx (transposed LDS).
// hh-part reads h_in (transposed global, coalesced b32).
__global__ __launch_bounds__(256) void k_lstm0(
    const float* __restrict__ Wih, const float* __restrict__ Whh,
    const float* __restrict__ bih, const float* __restrict__ bhh,
    const float* __restrict__ emb, const float* __restrict__ P,
    const float* __restrict__ h_in, float* __restrict__ h_out, float* __restrict__ c,
    const u64* __restrict__ amax_prev) {
  extern __shared__ float inT[];                 // [32][772]
  __shared__ int tok_lds[32];
  __shared__ float g_lds[2][4][32];
  const int t = threadIdx.x;
  if (t < 32) {
    u64 m = amax_prev[t];
#pragma unroll
    for (int s2 = 1; s2 < 8; ++s2) { const u64 o = amax_prev[s2 * 32 + t]; m = (o > m) ? o : m; }
    tok_lds[t] = (int)(0xFFFFFFFFu - (unsigned)(m & 0xFFFFFFFFull));
  }
  __syncthreads();
  {
    // embed rows: inT row n = emb[tok[n]][0..511]; contiguous LDS row, coalesced global
    const int half = t >> 7, c4 = (t & 127) * 4;
    for (int p = 0; p < 16; ++p) {
      const int n = p * 2 + half;
      *(float4*)(&inT[n * 772 + c4]) = *(const float4*)(emb + (size_t)tok_lds[n] * ND + c4);
    }
    // ctx transpose: inT[b][512+k] = P[(512+k)*32 + b]
    const int b = t & 31, kg = t >> 5;
    for (int k = kg; k < 256; k += 8) inT[b * 772 + 512 + k] = P[(512 + k) * 32 + b];
  }
  __syncthreads();
  const int dl = t >> 7, gate = (t >> 5) & 3, b = t & 31;
  const int d = blockIdx.x * 2 + dl;
  const int r = gate * ND + d;
  float acc = bih[r] + bhh[r];
  const float* wi = Wih + (size_t)r * 768;
  const float* pin = inT + b * 772;
#pragma unroll 4
  for (int k = 0; k < 768; k += 4) {
    const float4 w4 = *(const float4*)(wi + k);
    const float4 p4 = *(const float4*)(pin + k);
    acc += w4.x * p4.x + w4.y * p4.y + w4.z * p4.z + w4.w * p4.w;
  }
  const float* wh = Whh + (size_t)r * ND;
#pragma unroll 2
  for (int k = 0; k < ND; k += 4) {
    const float4 w4 = *(const float4*)(wh + k);
    acc += w4.x * h_in[(k + 0) * 32 + b] + w4.y * h_in[(k + 1) * 32 + b]
         + w4.z * h_in[(k + 2) * 32 + b] + w4.w * h_in[(k + 3) * 32 + b];
  }
  g_lds[dl][gate][b] = acc;
  __syncthreads();
  if (t < 64) {
    const int dl2 = t >> 5, b2 = t & 31;
    const int idx = (blockIdx.x * 2 + dl2) * 32 + b2;
    const float gi = g_lds[dl2][0][b2], gf = g_lds[dl2][1][b2];
    const float gg = g_lds[dl2][2][b2], go = g_lds[dl2][3][b2];
    const float cn = sigm(gf) * c[idx] + sigm(gi) * tanhf(gg);
    c[idx] = cn;
    h_out[idx] = sigm(go) * tanhf(cn);
  }
}

// ---------------- LSTM cell 1 ---------------- inT[b][0..511]=h0_new, [512..1023]=h1_cur
__global__ __launch_bounds__(256) void k_lstm1(
    const float* __restrict__ Wih, const float* __restrict__ Whh,
    const float* __restrict__ bih, const float* __restrict__ bhh,
    const float* __restrict__ h0n, const float* __restrict__ h1c,
    float* __restrict__ h1n, float* __restrict__ c, float* __restrict__ P) {
  extern __shared__ float inT[];                 // [32][1028]
  __shared__ float g_lds[2][4][32];
  const int t = threadIdx.x;
  {
    const int b = t & 31, kg = t >> 5;
    for (int k = kg; k < ND; k += 8) {
      inT[b * 1028 + k] = h0n[k * 32 + b];
      inT[b * 1028 + 512 + k] = h1c[k * 32 + b];
    }
  }
  __syncthreads();
  const int dl = t >> 7, gate = (t >> 5) & 3, b = t & 31;
  const int d = blockIdx.x * 2 + dl;
  const int r = gate * ND + d;
  float acc = bih[r] + bhh[r];
  const float* pin = inT + b * 1028;
  const float* wi = Wih + (size_t)r * ND;
#pragma unroll 4
  for (int k = 0; k < ND; k += 4) {
    const float4 w4 = *(const float4*)(wi + k);
    const float4 p4 = *(const float4*)(pin + k);
    acc += w4.x * p4.x + w4.y * p4.y + w4.z * p4.z + w4.w * p4.w;
  }
  const float* wh = Whh + (size_t)r * ND;
#pragma unroll 4
  for (int k = 0; k < ND; k += 4) {
    const float4 w4 = *(const float4*)(wh + k);
    const float4 p4 = *(const float4*)(pin + 512 + k);
    acc += w4.x * p4.x + w4.y * p4.y + w4.z * p4.z + w4.w * p4.w;
  }
  g_lds[dl][gate][b] = acc;
  __syncthreads();
  if (t < 64) {
    const int dl2 = t >> 5, b2 = t & 31;
    const int idx = (blockIdx.x * 2 + dl2) * 32 + b2;
    const float gi = g_lds[dl2][0][b2], gf = g_lds[dl2][1][b2];
    const float gg = g_lds[dl2][2][b2], go = g_lds[dl2][3][b2];
    const float cn = sigm(gf) * c[idx] + sigm(gi) * tanhf(gg);
    c[idx] = cn;
    const float hn = sigm(go) * tanhf(cn);
    h1n[idx] = hn;
    P[idx] = hn;
  }
}

// ---------------- attention: one block per batch row ----------------
// q/energy via coalesced row-loads + 32-lane shuffle reduce; ctx coalesced.
__global__ __launch_bounds__(256) void k_att(
    float* __restrict__ P, const float* __restrict__ Wq, const float* __restrict__ bq,
    const float* __restrict__ keys, const float* __restrict__ values,
    u64* __restrict__ amax_cur) {
  const int b = blockIdx.x, t = threadIdx.x;
  __shared__ float Pb[512];
  __shared__ float q_lds[256];
  __shared__ float sm[256];
  __shared__ float red[256];
  if (t < 8) amax_cur[t * 32 + b] = 0ull;
  Pb[t] = P[t * 32 + b];
  Pb[t + 256] = P[(t + 256) * 32 + b];
  __syncthreads();
  const int kl = t & 31, rh = (t >> 5) & 1, w = t >> 6;
  // q: wave w covers rows [w*64, w*64+64) in rh-pairs
  for (int p = 0; p < 32; ++p) {
    const int r = w * 64 + p * 2 + rh;
    const float* wq = Wq + (size_t)r * ND + kl * 4;
    float a = 0.f;
#pragma unroll
    for (int i = 0; i < 4; ++i) {
      const float4 w4 = *(const float4*)(wq + i * 128);
      const float4 p4 = *(const float4*)(Pb + i * 128 + kl * 4);
      a += w4.x * p4.x + w4.y * p4.y + w4.z * p4.z + w4.w * p4.w;
    }
#pragma unroll
    for (int mk = 1; mk < 32; mk <<= 1) a += __shfl_xor(a, mk);
    if (kl == 0) q_lds[r] = (a + bq[r]) * 0.0625f;  // 1/sqrt(256)
  }
  __syncthreads();
  // energy: s = p*8 + w*2 + rh covers 0..199 (guard s<196)
  for (int p = 0; p < 25; ++p) {
    const int s = p * 8 + w * 2 + rh;
    float a = 0.f;
    if (s < NS) {
      const float* kr = keys + ((size_t)b * NS + s) * NK + kl * 4;
#pragma unroll
      for (int i = 0; i < 2; ++i) {
        const float4 k4 = *(const float4*)(kr + i * 128);
        const float4 q4 = *(const float4*)(q_lds + i * 128 + kl * 4);
        a += k4.x * q4.x + k4.y * q4.y + k4.z * q4.z + k4.w * q4.w;
      }
    }
#pragma unroll
    for (int mk = 1; mk < 32; mk <<= 1) a += __shfl_xor(a, mk);
    if (kl == 0 && s < NS) sm[s] = a;
  }
  __syncthreads();
  // softmax over sm[0..195]
  const float e = (t < NS) ? sm[t] : -INFINITY;
  red[t] = e;
  __syncthreads();
  for (int off = 128; off; off >>= 1) { if (t < off) red[t] = fmaxf(red[t], red[t + off]); __syncthreads(); }
  const float mx = red[0];
  __syncthreads();
  const float a = (t < NS) ? expf(e - mx) : 0.f;
  red[t] = a;
  __syncthreads();
  for (int off = 128; off; off >>= 1) { if (t < off) red[t] += red[t + off]; __syncthreads(); }
  const float inv = 1.0f / red[0];
  sm[t] = a * inv;
  __syncthreads();
  // ctx: lanes over k-col (coalesced), s-loop broadcast from LDS
  {
    const float* vb = values + (size_t)b * NS * NK + t;
    float c0_ = 0.f, c1_ = 0.f, c2_ = 0.f, c3_ = 0.f;
    for (int s = 0; s < NS; s += 4) {
      c0_ += sm[s + 0] * vb[(size_t)(s + 0) * NK];
      c1_ += sm[s + 1] * vb[(size_t)(s + 1) * NK];
      c2_ += sm[s + 2] * vb[(size_t)(s + 2) * NK];
      c3_ += sm[s + 3] * vb[(size_t)(s + 3) * NK];
    }
    P[(512 + t) * 32 + b] = (c0_ + c1_) + (c2_ + c3_);
  }
}

// ---------------- pred GEMM (10000 x 32, K=768) ----------------
// 250 blocks x 40 v-rows. P transposed into LDS once; 5 rows/thread; W loads
// 2-line broadcast; VALU-bound (20 FMA-instr per 4k vs 6 mem-instr).
__global__ __launch_bounds__(256) void k_pred(
    const float* __restrict__ P, const float* __restrict__ Wp, const float* __restrict__ bp,
    float* __restrict__ out, u64* __restrict__ amax_cur, int step) {
  extern __shared__ float Pt[];                  // [32][772]
  __shared__ u64 cand[8][32];
  const int t = threadIdx.x;
  {
    const int b4 = (t & 7) * 4, kg = t >> 3;
    for (int k = kg; k < 768; k += 32) {
      const float4 v = *(const float4*)(P + (size_t)k * 32 + b4);
      Pt[(b4 + 0) * 772 + k] = v.x;
      Pt[(b4 + 1) * 772 + k] = v.y;
      Pt[(b4 + 2) * 772 + k] = v.z;
      Pt[(b4 + 3) * 772 + k] = v.w;
    }
  }
  __syncthreads();
  const int b = t & 31, rh = (t >> 5) & 1, w = t >> 6;
  const int rbase = blockIdx.x * 40 + w * 10 + rh;   // rows rbase + 2i, i=0..4
  float acc[5];
#pragma unroll
  for (int i = 0; i < 5; ++i) acc[i] = bp[rbase + 2 * i];
  const float* pb = Pt + b * 772;
#pragma unroll 2
  for (int k = 0; k < 768; k += 4) {
    const float4 p4 = *(const float4*)(pb + k);
#pragma unroll
    for (int i = 0; i < 5; ++i) {
      const float4 w4 = *(const float4*)(Wp + (size_t)(rbase + 2 * i) * 768 + k);
      acc[i] += w4.x * p4.x + w4.y * p4.y + w4.z * p4.z + w4.w * p4.w;
    }
  }
  const size_t ro = ((size_t)b * NT + step) * NV + rbase;
  u64 m = 0ull;
#pragma unroll
  for (int i = 0; i < 5; ++i) {
    out[ro + 2 * i] = acc[i];
    const u64 pk = packmax(acc[i], rbase + 2 * i);
    if (pk > m) m = pk;
  }
  cand[w * 2 + rh][b] = m;
  __syncthreads();
  if (t < 32) {
    u64 mm = cand[0][t];
#pragma unroll
    for (int i = 1; i < 8; ++i) { const u64 o = cand[i][t]; if (o > mm) mm = o; }
    atomicMax(&amax_cur[(blockIdx.x & 7) * 32 + t], mm);
  }
}

// ---------------- host ----------------
extern "C" void kernel_launch(void* const* d_in, const int* in_sizes, int n_in,
                              void* d_out, int out_size, void* d_ws, size_t ws_size,
                              hipStream_t stream) {
  (void)in_sizes; (void)n_in; (void)out_size; (void)ws_size;
  const float* x    = (const float*)d_in[0];
  const float* emb  = (const float*)d_in[1];
  const float* Wk   = (const float*)d_in[2];
  const float* bk   = (const float*)d_in[3];
  const float* Wv   = (const float*)d_in[4];
  const float* bv   = (const float*)d_in[5];
  const float* Wq   = (const float*)d_in[6];
  const float* bq   = (const float*)d_in[7];
  const float* Wp   = (const float*)d_in[8];
  const float* bp   = (const float*)d_in[9];
  const float* Wih0 = (const float*)d_in[10];
  const float* Whh0 = (const float*)d_in[11];
  const float* bih0 = (const float*)d_in[12];
  const float* bhh0 = (const float*)d_in[13];
  const float* Wih1 = (const float*)d_in[14];
  const float* Whh1 = (const float*)d_in[15];
  const float* bih1 = (const float*)d_in[16];
  const float* bhh1 = (const float*)d_in[17];
  float* out = (float*)d_out;

  const int LDS0 = 32 * 772 * 4;    // 98816 B
  const int LDS1 = 32 * 1028 * 4;   // 131584 B
  const int LDSP = 32 * 772 * 4;    // 98816 B
  // hedge: allow >64KB dynamic LDS (no-op / harmless if unsupported)
  (void)hipFuncSetAttribute((const void*)k_lstm0, hipFuncAttributeMaxDynamicSharedMemorySize, LDS0);
  (void)hipFuncSetAttribute((const void*)k_lstm1, hipFuncAttributeMaxDynamicSharedMemorySize, LDS1);
  (void)hipFuncSetAttribute((const void*)k_pred,  hipFuncAttributeMaxDynamicSharedMemorySize, LDSP);

  // workspace layout (floats)
  float* ws     = (float*)d_ws;
  float* keys   = ws;                        // 32*196*256 = 1605632
  float* values = keys + 1605632;            // 1605632
  float* h0t    = values + 1605632;          // [2][512*32] = 32768
  float* h1t    = h0t + 32768;               // 32768
  float* c0     = h1t + 32768;               // 16384
  float* c1     = c0 + 16384;                // 16384
  float* P      = c1 + 16384;                // [768][32] = 24576 (h1 | ctx)
  u64*   amax   = (u64*)(P + 24576);         // [2][8][32] packed argmax slots

  k_init<<<480, 256, 0, stream>>>(h0t, amax);
  k_kv<<<dim3(8, 32), 256, 0, stream>>>(x, Wk, bk, Wv, bv, keys, values);

  for (int step = 0; step < NT; ++step) {
    const int cur = step & 1, nxt = cur ^ 1;
    k_lstm0<<<256, 256, LDS0, stream>>>(Wih0, Whh0, bih0, bhh0, emb, P,
                                        h0t + cur * 16384, h0t + nxt * 16384, c0,
                                        amax + nxt * 256);
    k_lstm1<<<256, 256, LDS1, stream>>>(Wih1, Whh1, bih1, bhh1,
                                        h0t + nxt * 16384, h1t + cur * 16384,
                                        h1t + nxt * 16384, c1, P);
    k_att<<<32, 256, 0, stream>>>(P, Wq, bq, keys, values, amax + cur * 256);
    k_pred<<<250, 256, LDSP, stream>>>(P, Wp, bp, out, amax + cur * 256, step);
  }
}